// Round 9
// baseline (494.924 us; speedup 1.0000x reference)
//
#include <hip/hip_runtime.h>
#include <hip/hip_fp16.h>

// GCN 3-layer: fp16 intermediates, f32 accum, MFMA GEMMs, CSR build overlapped
// with layer-0 GEMM. Aggregation uses 16-lanes-per-row float4 gathers (4 rows
// per instruction, 4x MLP) + shfl_xor combine.
// Math: (x*ns)@W == (x@W)*ns_row; layer-0 folds ns[src] into the gather (fma),
// later layers pre-scale the agg output by ns (relu(x)*s == relu(x*s), s>0).

typedef _Float16 h8 __attribute__((ext_vector_type(8)));
typedef float f32x4 __attribute__((ext_vector_type(4)));

// ---------------- init: zero degree arrays + W -> fp16 transposed ----------------
__global__ void k_init(int* __restrict__ p, int n2,
                       const float* __restrict__ W0, const float* __restrict__ W1,
                       const float* __restrict__ W2, __half* __restrict__ Wt0,
                       __half* __restrict__ Wt1, __half* __restrict__ Wt2) {
    const int stride = gridDim.x * blockDim.x;
    for (int i = blockIdx.x * blockDim.x + threadIdx.x; i < n2; i += stride) p[i] = 0;
    for (int j = blockIdx.x * blockDim.x + threadIdx.x; j < 40960; j += stride) {
        if (j < 16384) {
            int nn = j >> 7, k = j & 127;
            Wt0[j] = __float2half(W0[k * 128 + nn]);
        } else if (j < 32768) {
            int i2 = j - 16384;
            int nn = i2 >> 7, k = i2 & 127;
            Wt1[i2] = __float2half(W1[k * 128 + nn]);
        } else {
            int i2 = j - 32768;
            int nn = i2 >> 7, k = i2 & 127;
            Wt2[i2] = __float2half(W2[k * 64 + nn]);
        }
    }
}

// ---------------- shared GEMM body: C[n,BN](fp16) = A[n,128] @ Wt[BN,128]^T ----------------
// v_mfma_f32_16x16x32_f16; A/B frag = 8 halves at k=8*(lane>>4), row/col=lane&15;
// C/D: col=lane&15, row=(lane>>4)*4+reg (guide m89-verified; round-6 validated).
template <int BN, bool F32A>
__device__ __forceinline__ void gemm_body(const void* __restrict__ Ap,
                                          const __half* __restrict__ Wt,
                                          __half* __restrict__ C, int n, int gb) {
    constexpr int K = 128, BM = 128, LDR = K + 8;  // halves; 272B rows
    __shared__ __half Al[BM * LDR];
    __shared__ __half Bl[BN * LDR];
    const int tid = threadIdx.x;
    const int row0 = gb * BM;
    if (F32A) {
        const float* A = (const float*)Ap;
#pragma unroll
        for (int q = 0; q < 16; ++q) {
            int fi = q * 256 + tid;
            int r = fi >> 5, c = (fi & 31) * 4;
            int gr = row0 + r;
            float4 v = make_float4(0.f, 0.f, 0.f, 0.f);
            if (gr < n) v = *(const float4*)(A + (size_t)gr * K + c);
            __half2 h0 = __floats2half2_rn(v.x, v.y);
            __half2 h1 = __floats2half2_rn(v.z, v.w);
            uint2 pk = make_uint2(*(unsigned*)&h0, *(unsigned*)&h1);
            *(uint2*)&Al[r * LDR + c] = pk;
        }
    } else {
        const __half* A = (const __half*)Ap;
#pragma unroll
        for (int q = 0; q < 8; ++q) {
            int fi = q * 256 + tid;
            int r = fi >> 4, c = (fi & 15) * 8;
            int gr = row0 + r;
            float4 v = make_float4(0.f, 0.f, 0.f, 0.f);
            if (gr < n) v = *(const float4*)(A + (size_t)gr * K + c);
            *(float4*)&Al[r * LDR + c] = v;
        }
    }
    // stage Wt tile (BN x 128 halves), pure float4 copy
#pragma unroll
    for (int q = 0; q < BN / 16; ++q) {
        int fi = q * 256 + tid;
        int r = fi >> 4, c = (fi & 15) * 8;
        *(float4*)&Bl[r * LDR + c] = *(const float4*)(Wt + (size_t)r * K + c);
    }
    __syncthreads();
    const int wid = tid >> 6, lane = tid & 63;
    const int lo = lane & 15, hi = lane >> 4;
    constexpr int NC = BN / 16;
    f32x4 acc[2][NC];
#pragma unroll
    for (int t = 0; t < 2; ++t)
#pragma unroll
        for (int c = 0; c < NC; ++c) acc[t][c] = (f32x4){0.f, 0.f, 0.f, 0.f};
#pragma unroll
    for (int kc = 0; kc < 4; ++kc) {
        h8 aF[2];
#pragma unroll
        for (int t = 0; t < 2; ++t)
            aF[t] = *(const h8*)&Al[(32 * wid + 16 * t + lo) * LDR + 32 * kc + 8 * hi];
#pragma unroll
        for (int c = 0; c < NC; ++c) {
            h8 bF = *(const h8*)&Bl[(16 * c + lo) * LDR + 32 * kc + 8 * hi];
#pragma unroll
            for (int t = 0; t < 2; ++t)
                acc[t][c] = __builtin_amdgcn_mfma_f32_16x16x32_f16(aF[t], bF, acc[t][c], 0, 0, 0);
        }
    }
#pragma unroll
    for (int t = 0; t < 2; ++t) {
#pragma unroll
        for (int j = 0; j < 4; ++j) {
            int gr = row0 + 32 * wid + 16 * t + 4 * hi + j;
            if (gr < n) {
#pragma unroll
                for (int c = 0; c < NC; ++c)
                    C[(size_t)gr * BN + 16 * c + lo] = __float2half(acc[t][c][j]);
            }
        }
    }
}

// ---------------- fused: {count deg + pos} || {GEMM0: Hu = feat @ W0} ----------------
__global__ __launch_bounds__(256) void k_fused0(
        const float* __restrict__ feat, const __half* __restrict__ Wt0,
        __half* __restrict__ Hu, int n,
        const int* __restrict__ src, const int* __restrict__ dst, int E,
        int* __restrict__ deg_o, int* __restrict__ deg_i, int* __restrict__ pos,
        int CB, int T) {
    const int b = blockIdx.x;
    const long lo = (long)b * CB / T, hi = (long)(b + 1) * CB / T;
    if (hi > lo) {  // count block, Bresenham-interleaved with GEMM blocks
        int i = (int)lo * 256 + threadIdx.x;
        const int stride = CB * 256;
        for (; i < E; i += stride) {
            atomicAdd(&deg_o[src[i]], 1);
            pos[i] = atomicAdd(&deg_i[dst[i]], 1);
        }
    } else {
        gemm_body<128, true>(feat, Wt0, Hu, n, b - (int)lo);
    }
}

// ---------------- plain GEMM (layers 1,2) ----------------
template <int BN>
__global__ __launch_bounds__(256) void k_gemm(const __half* __restrict__ X,
                                              const __half* __restrict__ Wt,
                                              __half* __restrict__ C, int n) {
    gemm_body<BN, false>(X, Wt, C, n, blockIdx.x);
}

// ---------------- scan1 + norms fused ----------------
__global__ __launch_bounds__(256) void k_scan1(const int* __restrict__ deg_i,
                                               const int* __restrict__ deg_o,
                                               int* __restrict__ rp,
                                               int* __restrict__ bsum,
                                               float* __restrict__ ns,
                                               float* __restrict__ nd, int n) {
    const int tid = threadIdx.x, lane = tid & 63, wid = tid >> 6;
    int i = blockIdx.x * 256 + tid;
    int v = (i < n) ? deg_i[i] : 0;
    if (i < n) {
        nd[i] = rsqrtf((float)max(v, 1));
        ns[i] = rsqrtf((float)max(deg_o[i], 1));
    }
    int x = v;
#pragma unroll
    for (int off = 1; off < 64; off <<= 1) {
        int t = __shfl_up(x, off, 64);
        if (lane >= off) x += t;
    }
    __shared__ int ws[4];
    if (lane == 63) ws[wid] = x;
    __syncthreads();
    int wo = 0;
    for (int k = 0; k < wid; ++k) wo += ws[k];
    int incl = wo + x;
    if (i < n) rp[i] = incl - v;              // block-local exclusive
    if (tid == 255) bsum[blockIdx.x] = incl;  // block total
}

// scan of block sums; rp[N] set so rp[N] + bsum[nb-1] == E
__global__ __launch_bounds__(512) void k_scan2(int* __restrict__ bsum, int nb,
                                               int* __restrict__ rpN) {
    __shared__ int s[512];
    const int tid = threadIdx.x;
    int v = (tid < nb) ? bsum[tid] : 0;
    s[tid] = v;
    __syncthreads();
    for (int off = 1; off < 512; off <<= 1) {
        int t = (tid >= off) ? s[tid - off] : 0;
        __syncthreads();
        s[tid] += t;
        __syncthreads();
    }
    if (tid < nb) bsum[tid] = s[tid] - v;  // exclusive block offsets
    if (tid == nb - 1) *rpN = v;           // last block's local total
}

// ---------------- CSR scatter (no atomics) ----------------
__global__ void k_scatter(const int* __restrict__ src, const int* __restrict__ dst, int E,
                          const int* __restrict__ rp, const int* __restrict__ bsum,
                          const int* __restrict__ pos, int* __restrict__ csr) {
    int i = blockIdx.x * blockDim.x + threadIdx.x;
    int stride = gridDim.x * blockDim.x;
    for (; i < E; i += stride) {
        int d = dst[i];
        csr[rp[d] + bsum[d >> 8] + pos[i]] = src[i];
    }
}

// ---------------- aggregation D=128: 16 lanes/row, float4/lane, 4 rows/instr ----------------
// SSCALE: fold ns[src] per edge (layer 0). Output fp16, pre-scaled by ns[node].
template <bool RELU, bool SSCALE>
__global__ __launch_bounds__(256) void k_agg128h(const __half* __restrict__ H,  // [N][128]
                                                 const int* __restrict__ rp,
                                                 const int* __restrict__ bsum,
                                                 const int* __restrict__ cs,
                                                 const float* __restrict__ nd,
                                                 const float* __restrict__ ns,
                                                 const float* __restrict__ b,
                                                 __half* __restrict__ out, int n) {
    const int wid = threadIdx.x >> 6, lane = threadIdx.x & 63;
    const int node = blockIdx.x * 4 + wid;
    if (node >= n) return;
    const int sub = lane >> 4, lo = lane & 15;  // 4 row-slots x 16 chunk-lanes
    const int beg = rp[node] + bsum[node >> 8];
    const int end = rp[node + 1] + bsum[(node + 1) >> 8];
    float a0[8], a1[8];
#pragma unroll
    for (int j = 0; j < 8; ++j) { a0[j] = 0.f; a1[j] = 0.f; }
    const float4 z = make_float4(0.f, 0.f, 0.f, 0.f);
    for (int e = beg; e < end; e += 8) {
        int i0 = e + sub, i1 = e + 4 + sub;
        bool p0 = i0 < end, p1 = i1 < end;
        int s0 = p0 ? cs[i0] : 0;
        int s1 = p1 ? cs[i1] : 0;
        float4 v0 = p0 ? *(const float4*)(H + (size_t)s0 * 128 + lo * 8) : z;
        float4 v1 = p1 ? *(const float4*)(H + (size_t)s1 * 128 + lo * 8) : z;
        float w0 = SSCALE ? ns[s0] : 1.f;
        float w1 = SSCALE ? ns[s1] : 1.f;
        const __half2* h0 = (const __half2*)&v0;
        const __half2* h1 = (const __half2*)&v1;
#pragma unroll
        for (int j = 0; j < 4; ++j) {
            float2 f0 = __half22float2(h0[j]);
            float2 f1 = __half22float2(h1[j]);
            if (SSCALE) {
                a0[2 * j] = fmaf(f0.x, w0, a0[2 * j]);
                a0[2 * j + 1] = fmaf(f0.y, w0, a0[2 * j + 1]);
                a1[2 * j] = fmaf(f1.x, w1, a1[2 * j]);
                a1[2 * j + 1] = fmaf(f1.y, w1, a1[2 * j + 1]);
            } else {
                a0[2 * j] += f0.x;
                a0[2 * j + 1] += f0.y;
                a1[2 * j] += f1.x;
                a1[2 * j + 1] += f1.y;
            }
        }
    }
    // combine 4 row-slots: xor over lane bits 4,5
#pragma unroll
    for (int j = 0; j < 8; ++j) {
        float v = a0[j] + a1[j];
        v += __shfl_xor(v, 16, 64);
        v += __shfl_xor(v, 32, 64);
        a0[j] = v;
    }
    if (sub == 0) {
        const float sc = nd[node];
        const float sn = ns[node];
        __half2 o[4];
#pragma unroll
        for (int j = 0; j < 4; ++j) {
            float ox = a0[2 * j] * sc + b[lo * 8 + 2 * j];
            float oy = a0[2 * j + 1] * sc + b[lo * 8 + 2 * j + 1];
            if (RELU) { ox = fmaxf(ox, 0.f); oy = fmaxf(oy, 0.f); }
            o[j] = __floats2half2_rn(ox * sn, oy * sn);
        }
        *(float4*)(out + (size_t)node * 128 + lo * 8) = *(float4*)&o[0];
    }
}

// ---------------- aggregation D=64: 8 lanes/row, float4/lane, 8 rows/instr; f32 out ----------------
__global__ __launch_bounds__(256) void k_agg64h(const __half* __restrict__ H,  // [N][64]
                                                const int* __restrict__ rp,
                                                const int* __restrict__ bsum,
                                                const int* __restrict__ cs,
                                                const float* __restrict__ nd,
                                                const float* __restrict__ b,
                                                float* __restrict__ out, int n) {
    const int wid = threadIdx.x >> 6, lane = threadIdx.x & 63;
    const int node = blockIdx.x * 4 + wid;
    if (node >= n) return;
    const int sub = lane >> 3, lo = lane & 7;  // 8 row-slots x 8 chunk-lanes
    const int beg = rp[node] + bsum[node >> 8];
    const int end = rp[node + 1] + bsum[(node + 1) >> 8];
    float a0[8], a1[8];
#pragma unroll
    for (int j = 0; j < 8; ++j) { a0[j] = 0.f; a1[j] = 0.f; }
    const float4 z = make_float4(0.f, 0.f, 0.f, 0.f);
    for (int e = beg; e < end; e += 16) {
        int i0 = e + sub, i1 = e + 8 + sub;
        bool p0 = i0 < end, p1 = i1 < end;
        int s0 = p0 ? cs[i0] : 0;
        int s1 = p1 ? cs[i1] : 0;
        float4 v0 = p0 ? *(const float4*)(H + (size_t)s0 * 64 + lo * 8) : z;
        float4 v1 = p1 ? *(const float4*)(H + (size_t)s1 * 64 + lo * 8) : z;
        const __half2* h0 = (const __half2*)&v0;
        const __half2* h1 = (const __half2*)&v1;
#pragma unroll
        for (int j = 0; j < 4; ++j) {
            float2 f0 = __half22float2(h0[j]);
            float2 f1 = __half22float2(h1[j]);
            a0[2 * j] += f0.x;
            a0[2 * j + 1] += f0.y;
            a1[2 * j] += f1.x;
            a1[2 * j + 1] += f1.y;
        }
    }
    // combine 8 row-slots: xor over lane bits 3,4,5
#pragma unroll
    for (int j = 0; j < 8; ++j) {
        float v = a0[j] + a1[j];
        v += __shfl_xor(v, 8, 64);
        v += __shfl_xor(v, 16, 64);
        v += __shfl_xor(v, 32, 64);
        a0[j] = v;
    }
    if (sub == 0) {
        const float sc = nd[node];
        float o[8];
#pragma unroll
        for (int j = 0; j < 8; ++j) o[j] = a0[j] * sc + b[lo * 8 + j];
        *(float4*)(out + (size_t)node * 64 + lo * 8) = *(float4*)&o[0];
        *(float4*)(out + (size_t)node * 64 + lo * 8 + 4) = *(float4*)&o[4];
    }
}

extern "C" void kernel_launch(void* const* d_in, const int* in_sizes, int n_in,
                              void* d_out, int out_size, void* d_ws, size_t ws_size,
                              hipStream_t stream) {
    const float* feat = (const float*)d_in[0];
    const int* ei = (const int*)d_in[1];
    const float* W0 = (const float*)d_in[2];
    const float* b0 = (const float*)d_in[3];
    const float* W1 = (const float*)d_in[4];
    const float* b1 = (const float*)d_in[5];
    const float* W2 = (const float*)d_in[6];
    const float* b2 = (const float*)d_in[7];
    float* out = (float*)d_out;

    const int N = in_sizes[0] / 128;  // 100000
    const int E = in_sizes[1] / 2;    // 1600000
    const int* src = ei;
    const int* dst = ei + E;
    const int NB = (N + 255) / 256;   // scan blocks (391 <= 512)

    // workspace layout (16B-aligned chunks)
    char* w = (char*)d_ws;
    float* norm_src = (float*)w; w += (size_t)N * 4;
    float* norm_dst = (float*)w; w += (size_t)N * 4;
    int* deg_o = (int*)w;        w += (size_t)N * 4;   // deg_o,deg_i contiguous (zero 2N)
    int* deg_i = (int*)w;        w += (size_t)N * 4;
    int* rp    = (int*)w;        w += ((size_t)(N + 1) * 4 + 15) / 16 * 16;
    int* bsum  = (int*)w;        w += 512 * 4;
    int* pos   = (int*)w;        w += (size_t)E * 4;
    int* csr   = (int*)w;        w += (size_t)E * 4;
    __half* Wt0 = (__half*)w;    w += 128 * 128 * 2;
    __half* Wt1 = (__half*)w;    w += 128 * 128 * 2;
    __half* Wt2 = (__half*)w;    w += 128 * 64 * 2;
    __half* Hb = (__half*)w;     w += (size_t)N * 128 * 2;  // GEMM out (gather src)
    __half* Xb = (__half*)w;     w += (size_t)N * 128 * 2;  // agg out / next GEMM in

    const int GB = (N + 127) / 128;   // 782 GEMM blocks
    const int CB = 1024;              // count blocks
    const int T = GB + CB;

    k_init<<<512, 256, 0, stream>>>(deg_o, 2 * N, W0, W1, W2, Wt0, Wt1, Wt2);
    // count || GEMM0 (Hu = feat @ W0, unscaled)
    k_fused0<<<T, 256, 0, stream>>>(feat, Wt0, Hb, N, src, dst, E, deg_o, deg_i, pos, CB, T);
    k_scan1<<<NB, 256, 0, stream>>>(deg_i, deg_o, rp, bsum, norm_src, norm_dst, N);
    k_scan2<<<1, 512, 0, stream>>>(bsum, NB, rp + N);
    k_scatter<<<2048, 256, 0, stream>>>(src, dst, E, rp, bsum, pos, csr);

    const int agg_grid = (N + 3) / 4;
    // layer 0: gather Hb with per-edge ns[src]; out pre-scaled by ns
    k_agg128h<true, true><<<agg_grid, 256, 0, stream>>>(Hb, rp, bsum, csr,
                                                        norm_dst, norm_src, b0, Xb, N);
    // layer 1
    k_gemm<128><<<GB, 256, 0, stream>>>(Xb, Wt1, Hb, N);
    k_agg128h<true, false><<<agg_grid, 256, 0, stream>>>(Hb, rp, bsum, csr,
                                                         norm_dst, norm_src, b1, Xb, N);
    // layer 2 (BN=64, no relu, f32 out)
    k_gemm<64><<<GB, 256, 0, stream>>>(Xb, Wt2, Hb, N);
    k_agg64h<<<agg_grid, 256, 0, stream>>>(Hb, rp, bsum, csr, norm_dst, b2, out, N);
}